// Round 8
// baseline (714.731 us; speedup 1.0000x reference)
//
#include <hip/hip_runtime.h>
#include <hip/hip_bf16.h>
#include <stdint.h>
#include <stddef.h>

// GRU policy: B=2048, T=100, H=256, IN=48 (32 state + 16 ref), ACT=2.
// R8: k_xg1 ELIMINATED. Role1 computes its own xg1 slice in a pre-phase:
//     af[6][8] (w_ih1) asm-forced resident (192 regs), streams out0(c-1)
//     B-tiles, 48 MFMA/tt, stores private xg slice; af released before wf
//     load (disjoint lifetimes -> same physical regs). Launch = max(role0
//     87us, role1 10+80us). out0c double-buffered by chunk parity.
//     6 dispatches total. (R7 post-mortem: k_xg1 LDS staging regressed ->
//     reverted; barrier_lgkm neutral in fused -> kept, harmless.)

#define OBS_STRIDE 1632
#define H 256
#define M 16
#define THREADS 512

typedef __attribute__((ext_vector_type(8))) short bfrag8;   // 8 bf16 (4 VGPR)
typedef __attribute__((ext_vector_type(4))) short bfrag4;   // 4 bf16 (8B)
typedef __attribute__((ext_vector_type(4))) float floatx4;  // MFMA C/D

#define MFMA16(a, b, c) __builtin_amdgcn_mfma_f32_16x16x32_bf16((a), (b), (c), 0, 0, 0)

__device__ __forceinline__ unsigned short f2bf(float f) {
  union { float f; unsigned int i; } v; v.f = f;
  unsigned int i = v.i + 0x7FFFu + ((v.i >> 16) & 1u);  // RNE
  return (unsigned short)(i >> 16);
}
__device__ __forceinline__ float bf2f(unsigned short u) {
  union { unsigned int i; float f; } v; v.i = ((unsigned int)u) << 16; return v.f;
}
// sigmoid(x) = rcp(1 + 2^(-x*log2e)); saturates correctly, no clamps.
__device__ __forceinline__ float fsigm(float x) {
  return __builtin_amdgcn_rcpf(1.f + __builtin_amdgcn_exp2f(-1.44269504f * x));
}
// tanh(x) = 1 - 2*rcp(1 + 2^(x*2log2e)); saturates correctly, no clamps.
__device__ __forceinline__ float ftanh(float x) {
  return 1.f - 2.f * __builtin_amdgcn_rcpf(1.f + __builtin_amdgcn_exp2f(2.88539008f * x));
}

// Forced (non-rematerializable) 16B global load -> stays in VGPR/AGPR file.
__device__ __forceinline__ void ld16_async(bfrag8& d, const unsigned short* p) {
  asm volatile("global_load_dwordx4 %0, %1, off" : "=v"(d) : "v"(p));
}
__device__ __forceinline__ void wait6(bfrag8& a, bfrag8& b, bfrag8& c,
                                      bfrag8& d, bfrag8& e, bfrag8& f) {
  asm volatile("s_waitcnt vmcnt(0)"
               : "+v"(a), "+v"(b), "+v"(c), "+v"(d), "+v"(e), "+v"(f) :: "memory");
}
// Workgroup barrier that drains LDS only (skips the vmcnt(0) store-ack drain
// the compiler emits for __syncthreads).
__device__ __forceinline__ void barrier_lgkm() {
  asm volatile("s_waitcnt lgkmcnt(0)\n\ts_barrier" ::: "memory");
}

// ---------------------------------------------------------------- k_prep
__global__ void k_prep(const float* __restrict__ wih0, const float* __restrict__ whh0,
                       const float* __restrict__ wih1, const float* __restrict__ whh1,
                       unsigned short* __restrict__ o_wihs, unsigned short* __restrict__ o_wihr,
                       unsigned short* __restrict__ o_whh0,
                       unsigned short* __restrict__ o_wih1, unsigned short* __restrict__ o_whh1,
                       float* __restrict__ h0, float* __restrict__ h1) {
  long idx = (long)blockIdx.x * blockDim.x + threadIdx.x;
  const long ns = 768L * 32, n1 = 768L * 256, nh = 2048L * 256;
  if (idx < ns) { long r = idx >> 5, c = idx & 31;
                  o_wihs[idx] = f2bf(wih0[r * 48 + c]); return; }
  idx -= ns;
  if (idx < ns) { long r = idx >> 5, c = idx & 31;
                  o_wihr[idx] = (c < 16) ? f2bf(wih0[r * 48 + 32 + c]) : (unsigned short)0; return; }
  idx -= ns;
  if (idx < n1) { o_whh0[idx] = f2bf(whh0[idx]); return; }
  idx -= n1;
  if (idx < n1) { o_wih1[idx] = f2bf(wih1[idx]); return; }
  idx -= n1;
  if (idx < n1) { o_whh1[idx] = f2bf(whh1[idx]); return; }
  idx -= n1;
  if (idx < nh) { h0[idx] = 0.f; return; }
  idx -= nh;
  if (idx < nh) { h1[idx] = 0.f; return; }
}

// ---------------------------------------------------------------- k_fused
// 256 WGs: blocks 0..127 = layer0 chunk c, blocks 128..255 = layer1 chunk c-1
// (with a self-serve xg1 pre-phase reading out0(c-1)).
// Per role: 16 batch rows/WG. Wave wv owns h-cols [32wv,32wv+32):
// tiles f0..5={r0,r1,z0,z1,n0,n1}, nt=(f>>1)*16+2*wv+(f&1).
__global__ __launch_bounds__(THREADS, 2) void k_fused(
    const float* __restrict__ obs,
    const unsigned short* __restrict__ g_wihs,  // [768][32]
    const unsigned short* __restrict__ g_wihr,  // [768][32] (hi 16 zero)
    const unsigned short* __restrict__ g_whh0,  // [768][256]
    const float* __restrict__ b_ih0, const float* __restrict__ b_hh0,
    float* __restrict__ h0state,
    unsigned short* __restrict__ out0w,         // [Tc][2048][256]  (role0 writes)
    const unsigned short* __restrict__ out0r,   // [Tc][2048][256]  (role1 reads)
    unsigned short* __restrict__ xg1c,          // [Tc][128][768][16] (role1 w+r)
    const unsigned short* __restrict__ g_wih1,  // [768][256]
    const unsigned short* __restrict__ g_whh1,  // [768][256]
    const float* __restrict__ b_ih1, const float* __restrict__ b_hh1,
    float* __restrict__ h1state,
    const float* __restrict__ fc_w, const float* __restrict__ fc_b,
    const float* __restrict__ act_high, const float* __restrict__ act_low,
    float* __restrict__ dout,
    int t0, int Tc, int do_l0, int do_l1, int is_last) {
  __shared__ __align__(16) unsigned short s_mem[71936];

  const int tid = threadIdx.x;
  const int wv = tid >> 6, lane = tid & 63, ln = lane & 15, qd = lane >> 4;
  const int role = blockIdx.x >> 7;          // 0 = layer0, 1 = layer1
  const int bblk = blockIdx.x & 127;
  const int b0 = bblk * M;

  if (role == 0) {
    // ======================= LAYER 0 =======================
    if (!do_l0) return;
    unsigned short* s_whh6 = s_mem;           // [768*40]
    unsigned short* s_whh7 = s_mem + 30720;   // [768*40]
    unsigned short* s_hA   = s_mem + 61440;   // [2][16*264]
    unsigned short* s_x    = s_mem + 69888;   // [2][16*32]
    unsigned short* s_st   = s_mem + 70912;   // [16*32]

    for (int i = tid * 8; i < 768 * 32; i += THREADS * 8) {
      int m = i >> 5, c = i & 31;
      *(bfrag8*)&s_whh6[m * 40 + c] = *(const bfrag8*)&g_whh0[m * 256 + 192 + c];
      *(bfrag8*)&s_whh7[m * 40 + c] = *(const bfrag8*)&g_whh0[m * 256 + 224 + c];
    }
    { int r = tid >> 5, c = tid & 31;
      s_st[tid] = f2bf(obs[(size_t)(b0 + r) * OBS_STRIDE + c]); }
    if (tid < 256) {
      int r = tid >> 4, c = tid & 15;
      s_x[r * 32 + c] = f2bf(obs[(size_t)(b0 + r) * OBS_STRIDE + 32 + (size_t)t0 * 16 + c]);
      s_x[r * 32 + 16 + c] = 0;
      s_x[512 + r * 32 + 16 + c] = 0;
    }

    bfrag8 wf[6][6];  // forced-resident w_hh0 ks0..5
#pragma unroll
    for (int ks = 0; ks < 6; ++ks) {
#pragma unroll
      for (int f = 0; f < 6; ++f) {
        int nt = (f >> 1) * 16 + 2 * wv + (f & 1);
        ld16_async(wf[f][ks], g_whh0 + (size_t)(nt * 16 + ln) * 256 + ks * 32 + qd * 8);
      }
      wait6(wf[0][ks], wf[1][ks], wf[2][ks], wf[3][ks], wf[4][ks], wf[5][ks]);
    }
    bfrag8 wir[6];
#pragma unroll
    for (int f = 0; f < 6; ++f) {
      int nt = (f >> 1) * 16 + 2 * wv + (f & 1);
      wir[f] = *(const bfrag8*)&g_wihr[(size_t)(nt * 16 + ln) * 32 + qd * 8];
    }
    float bias_hn[2];
#pragma unroll
    for (int p = 0; p < 2; ++p) bias_hn[p] = b_hh0[512 + wv * 32 + p * 16 + ln];

    float h[2][4];
#pragma unroll
    for (int p = 0; p < 2; ++p)
#pragma unroll
      for (int i = 0; i < 4; ++i)
        h[p][i] = h0state[(size_t)(b0 + qd * 4 + i) * H + wv * 32 + p * 16 + ln];

    __syncthreads();

    // time-invariant state GEMM + bias fold
    floatx4 cc[6];
    {
      bfrag8 a_st = *(const bfrag8*)&s_st[ln * 32 + qd * 8];
#pragma unroll
      for (int f = 0; f < 6; ++f) {
        int nt = (f >> 1) * 16 + 2 * wv + (f & 1);
        int m = nt * 16 + ln;
        bfrag8 b_st = *(const bfrag8*)&g_wihs[(size_t)m * 32 + qd * 8];
        cc[f] = MFMA16(a_st, b_st, ((floatx4){0.f, 0.f, 0.f, 0.f}));
        float badd = b_ih0[m] + ((f < 4) ? b_hh0[m] : 0.f);
#pragma unroll
        for (int i = 0; i < 4; ++i) cc[f][i] += badd;
      }
    }
#pragma unroll
    for (int p = 0; p < 2; ++p)
#pragma unroll
      for (int i = 0; i < 4; ++i)
        s_hA[(qd * 4 + i) * 264 + wv * 32 + p * 16 + ln] = f2bf(h[p][i]);
    __syncthreads();

    const int orow = tid >> 5, ocol = (tid & 31) * 8;
    for (int tt = 0; tt < Tc; ++tt) {
      const int cur = tt & 1, nxt = cur ^ 1;
      // coalesced out0 store of PREVIOUS step's h from s_hA[cur] (stable now)
      if (tt > 0) {
        bfrag8 hv = *(const bfrag8*)&s_hA[cur * 4224 + orow * 264 + ocol];
        *(bfrag8*)&out0w[((size_t)(tt - 1) * 2048 + b0 + orow) * 256 + ocol] = hv;
      }
      float nref = 0.f;
      {
        int tl = (tt + 1 < Tc) ? tt + 1 : tt;
        if (tid < 256)
          nref = obs[(size_t)(b0 + (tid >> 4)) * OBS_STRIDE + 32 +
                     (size_t)(t0 + tl) * 16 + (tid & 15)];
      }

      floatx4 C[8];  // 0,1=r 2,3=z 4,5=xn 6,7=hn
#pragma unroll
      for (int f = 0; f < 6; ++f) C[f] = cc[f];
      C[6] = (floatx4){0.f, 0.f, 0.f, 0.f};
      C[7] = (floatx4){0.f, 0.f, 0.f, 0.f};

      {  // ref GEMM (K=32, hi half zero)
        bfrag8 ax = *(const bfrag8*)&s_x[cur * 512 + ln * 32 + qd * 8];
        C[0] = MFMA16(ax, wir[0], C[0]);
        C[1] = MFMA16(ax, wir[1], C[1]);
        C[2] = MFMA16(ax, wir[2], C[2]);
        C[3] = MFMA16(ax, wir[3], C[3]);
        C[4] = MFMA16(ax, wir[4], C[4]);
        C[5] = MFMA16(ax, wir[5], C[5]);
      }
#pragma unroll
      for (int ks = 0; ks < 6; ++ks) {
        bfrag8 ah = *(const bfrag8*)&s_hA[cur * 4224 + ln * 264 + ks * 32 + qd * 8];
        C[0] = MFMA16(ah, wf[0][ks], C[0]);
        C[1] = MFMA16(ah, wf[1][ks], C[1]);
        C[2] = MFMA16(ah, wf[2][ks], C[2]);
        C[3] = MFMA16(ah, wf[3][ks], C[3]);
        C[6] = MFMA16(ah, wf[4][ks], C[6]);
        C[7] = MFMA16(ah, wf[5][ks], C[7]);
      }
      {  // ks6 strip
        bfrag8 ah = *(const bfrag8*)&s_hA[cur * 4224 + ln * 264 + 192 + qd * 8];
#pragma unroll
        for (int f = 0; f < 6; ++f) {
          int nt = (f >> 1) * 16 + 2 * wv + (f & 1);
          bfrag8 bh = *(const bfrag8*)&s_whh6[(nt * 16 + ln) * 40 + qd * 8];
          int ci = (f < 4) ? f : f + 2;
          C[ci] = MFMA16(ah, bh, C[ci]);
        }
      }
      {  // ks7 strip
        bfrag8 ah = *(const bfrag8*)&s_hA[cur * 4224 + ln * 264 + 224 + qd * 8];
#pragma unroll
        for (int f = 0; f < 6; ++f) {
          int nt = (f >> 1) * 16 + 2 * wv + (f & 1);
          bfrag8 bh = *(const bfrag8*)&s_whh7[(nt * 16 + ln) * 40 + qd * 8];
          int ci = (f < 4) ? f : f + 2;
          C[ci] = MFMA16(ah, bh, C[ci]);
        }
      }
#pragma unroll
      for (int p = 0; p < 2; ++p)
#pragma unroll
        for (int i = 0; i < 4; ++i) {
          float r = fsigm(C[0 + p][i]);
          float z = fsigm(C[2 + p][i]);
          float n = ftanh(C[4 + p][i] + r * (C[6 + p][i] + bias_hn[p]));
          h[p][i] = n + z * (h[p][i] - n);
          s_hA[nxt * 4224 + (qd * 4 + i) * 264 + wv * 32 + p * 16 + ln] = f2bf(h[p][i]);
        }
      if (tid < 256) s_x[nxt * 512 + (tid >> 4) * 32 + (tid & 15)] = f2bf(nref);
      barrier_lgkm();
    }
    // final out0 store + h0 carry
    {
      const int fb = Tc & 1;
      bfrag8 hv = *(const bfrag8*)&s_hA[fb * 4224 + orow * 264 + ocol];
      *(bfrag8*)&out0w[((size_t)(Tc - 1) * 2048 + b0 + orow) * 256 + ocol] = hv;
    }
#pragma unroll
    for (int p = 0; p < 2; ++p)
#pragma unroll
      for (int i = 0; i < 4; ++i)
        h0state[(size_t)(b0 + qd * 4 + i) * H + wv * 32 + p * 16 + ln] = h[p][i];

  } else {
    // ======================= LAYER 1 =======================
    if (!do_l1) return;
    unsigned short* s_whh7 = s_mem;           // [768*40]
    unsigned short* s_hA   = s_mem + 30720;   // [2][16*264]

    // ---- PRE-PHASE: compute this WG's xg1 slice from out0r ----
    // Wave wv owns xg gate-tiles wv*6..wv*6+5 (all 768 gates across 8 waves).
    // af is released before wf loads below (disjoint lifetimes).
    {
      bfrag8 af[6][8];  // forced-resident w_ih_l1 A-fragments (192 regs)
#pragma unroll
      for (int ks = 0; ks < 8; ++ks) {
#pragma unroll
        for (int f = 0; f < 6; ++f) {
          ld16_async(af[f][ks],
                     g_wih1 + (size_t)((wv * 6 + f) * 16 + ln) * 256 + ks * 32 + qd * 8);
        }
        wait6(af[0][ks], af[1][ks], af[2][ks], af[3][ks], af[4][ks], af[5][ks]);
      }
      for (int tt = 0; tt < Tc; ++tt) {
        const unsigned short* brow = out0r + ((size_t)tt * 2048 + b0 + ln) * 256 + qd * 8;
        floatx4 Cx[6];
#pragma unroll
        for (int f = 0; f < 6; ++f) Cx[f] = (floatx4){0.f, 0.f, 0.f, 0.f};
#pragma unroll
        for (int ks = 0; ks < 8; ++ks) {
          bfrag8 bfr = *(const bfrag8*)(brow + ks * 32);
          Cx[0] = MFMA16(af[0][ks], bfr, Cx[0]);
          Cx[1] = MFMA16(af[1][ks], bfr, Cx[1]);
          Cx[2] = MFMA16(af[2][ks], bfr, Cx[2]);
          Cx[3] = MFMA16(af[3][ks], bfr, Cx[3]);
          Cx[4] = MFMA16(af[4][ks], bfr, Cx[4]);
          Cx[5] = MFMA16(af[5][ks], bfr, Cx[5]);
        }
        const size_t obase = ((size_t)tt * 128 + bblk) * (768 * 16);
#pragma unroll
        for (int f = 0; f < 6; ++f) {
          int nt = wv * 6 + f;
#pragma unroll
          for (int i = 0; i < 4; ++i) {
            int m = nt * 16 + qd * 4 + i;
            xg1c[obase + (size_t)m * 16 + ln] = f2bf(Cx[f][i]);
          }
        }
      }
    }

    // ---- main phase setup (wf loads' vmcnt(0) waits also drain the
    //      pre-phase xg1c stores before any xg read below) ----
    for (int i = tid * 8; i < 768 * 32; i += THREADS * 8) {
      int m = i >> 5, c = i & 31;
      *(bfrag8*)&s_whh7[m * 40 + c] = *(const bfrag8*)&g_whh1[m * 256 + 224 + c];
    }
    bfrag8 wf[6][7];  // forced-resident w_hh1 ks0..6
#pragma unroll
    for (int ks = 0; ks < 7; ++ks) {
#pragma unroll
      for (int f = 0; f < 6; ++f) {
        int nt = (f >> 1) * 16 + 2 * wv + (f & 1);
        ld16_async(wf[f][ks], g_whh1 + (size_t)(nt * 16 + ln) * 256 + ks * 32 + qd * 8);
      }
      wait6(wf[0][ks], wf[1][ks], wf[2][ks], wf[3][ks], wf[4][ks], wf[5][ks]);
    }
    float bias_r[2], bias_z[2], bias_xn[2], bias_hn[2];
#pragma unroll
    for (int p = 0; p < 2; ++p) {
      int col = wv * 32 + p * 16 + ln;
      bias_r[p] = b_ih1[col] + b_hh1[col];
      bias_z[p] = b_ih1[256 + col] + b_hh1[256 + col];
      bias_xn[p] = b_ih1[512 + col];
      bias_hn[p] = b_hh1[512 + col];
    }
    float h[2][4];
#pragma unroll
    for (int p = 0; p < 2; ++p)
#pragma unroll
      for (int i = 0; i < 4; ++i)
        h[p][i] = h1state[(size_t)(b0 + qd * 4 + i) * H + wv * 32 + p * 16 + ln];
#pragma unroll
    for (int p = 0; p < 2; ++p)
#pragma unroll
      for (int i = 0; i < 4; ++i)
        s_hA[(qd * 4 + i) * 264 + wv * 32 + p * 16 + ln] = f2bf(h[p][i]);

    size_t offx[2][3];
#pragma unroll
    for (int p = 0; p < 2; ++p) {
      int col = wv * 32 + p * 16 + ln;
#pragma unroll
      for (int g = 0; g < 3; ++g)
        offx[p][g] = (size_t)(g * 256 + col) * 16 + qd * 4;
    }
    bfrag4 xr[2], xz[2], xn[2];
    {
      const unsigned short* xb = xg1c + (size_t)bblk * (768 * 16);
#pragma unroll
      for (int p = 0; p < 2; ++p) {
        xr[p] = *(const bfrag4*)&xb[offx[p][0]];
        xz[p] = *(const bfrag4*)&xb[offx[p][1]];
        xn[p] = *(const bfrag4*)&xb[offx[p][2]];
      }
    }
    __syncthreads();

    for (int tt = 0; tt < Tc; ++tt) {
      const int cur = tt & 1, nxt = cur ^ 1;
      bfrag4 nxr[2], nxz[2], nxn[2];
      {
        int tl = (tt + 1 < Tc) ? tt + 1 : tt;
        const unsigned short* xb = xg1c + ((size_t)tl * 128 + bblk) * (768 * 16);
#pragma unroll
        for (int p = 0; p < 2; ++p) {
          nxr[p] = *(const bfrag4*)&xb[offx[p][0]];
          nxz[p] = *(const bfrag4*)&xb[offx[p][1]];
          nxn[p] = *(const bfrag4*)&xb[offx[p][2]];
        }
      }

      floatx4 C[6];  // 0,1=r 2,3=z 4,5=hn
#pragma unroll
      for (int i = 0; i < 6; ++i) C[i] = (floatx4){0.f, 0.f, 0.f, 0.f};
#pragma unroll
      for (int ks = 0; ks < 7; ++ks) {
        bfrag8 ah = *(const bfrag8*)&s_hA[cur * 4224 + ln * 264 + ks * 32 + qd * 8];
        C[0] = MFMA16(ah, wf[0][ks], C[0]);
        C[1] = MFMA16(ah, wf[1][ks], C[1]);
        C[2] = MFMA16(ah, wf[2][ks], C[2]);
        C[3] = MFMA16(ah, wf[3][ks], C[3]);
        C[4] = MFMA16(ah, wf[4][ks], C[4]);
        C[5] = MFMA16(ah, wf[5][ks], C[5]);
      }
      {
        bfrag8 ah = *(const bfrag8*)&s_hA[cur * 4224 + ln * 264 + 224 + qd * 8];
#pragma unroll
        for (int f = 0; f < 6; ++f) {
          int nt = (f >> 1) * 16 + 2 * wv + (f & 1);
          bfrag8 bh = *(const bfrag8*)&s_whh7[(nt * 16 + ln) * 40 + qd * 8];
          C[f] = MFMA16(ah, bh, C[f]);
        }
      }
#pragma unroll
      for (int p = 0; p < 2; ++p)
#pragma unroll
        for (int i = 0; i < 4; ++i) {
          float r = fsigm(C[0 + p][i] + bf2f((unsigned short)xr[p][i]) + bias_r[p]);
          float z = fsigm(C[2 + p][i] + bf2f((unsigned short)xz[p][i]) + bias_z[p]);
          float n = ftanh(bf2f((unsigned short)xn[p][i]) + bias_xn[p] +
                          r * (C[4 + p][i] + bias_hn[p]));
          h[p][i] = n + z * (h[p][i] - n);
          s_hA[nxt * 4224 + (qd * 4 + i) * 264 + wv * 32 + p * 16 + ln] = f2bf(h[p][i]);
        }
#pragma unroll
      for (int p = 0; p < 2; ++p) { xr[p] = nxr[p]; xz[p] = nxz[p]; xn[p] = nxn[p]; }
      barrier_lgkm();
    }
#pragma unroll
    for (int p = 0; p < 2; ++p)
#pragma unroll
      for (int i = 0; i < 4; ++i)
        h1state[(size_t)(b0 + qd * 4 + i) * H + wv * 32 + p * 16 + ln] = h[p][i];

    if (is_last) {
      // parallel FC tail: tid = r*32 + a*16 + kseg
      const int fb = Tc & 1;
      int r = tid >> 5, a = (tid >> 4) & 1, kseg = tid & 15;
      float acc = 0.f;
#pragma unroll
      for (int j = 0; j < 16; ++j) {
        int k = kseg * 16 + j;
        acc += bf2f(s_hA[fb * 4224 + r * 264 + k]) * fc_w[a * H + k];
      }
      acc += __shfl_down(acc, 8);
      acc += __shfl_down(acc, 4);
      acc += __shfl_down(acc, 2);
      acc += __shfl_down(acc, 1);
      if (kseg == 0) {
        acc += fc_b[a];
        float hi = act_high[a], lo = act_low[a];
        float th = ftanh(acc);
        dout[(size_t)(b0 + r) * 2 + a] = 0.5f * (hi - lo) * th + 0.5f * (hi + lo);
      }
    }
  }
}

// ---------------------------------------------------------------- host
extern "C" void kernel_launch(void* const* d_in, const int* in_sizes, int n_in,
                              void* d_out, int out_size, void* d_ws, size_t ws_size,
                              hipStream_t stream) {
  const float* obs  = (const float*)d_in[0];
  const float* wih0 = (const float*)d_in[1];
  const float* whh0 = (const float*)d_in[2];
  const float* bih0 = (const float*)d_in[3];
  const float* bhh0 = (const float*)d_in[4];
  const float* wih1 = (const float*)d_in[5];
  const float* whh1 = (const float*)d_in[6];
  const float* bih1 = (const float*)d_in[7];
  const float* bhh1 = (const float*)d_in[8];
  const float* fcw  = (const float*)d_in[9];
  const float* fcb  = (const float*)d_in[10];
  const float* ahigh= (const float*)d_in[11];
  const float* alow = (const float*)d_in[12];

  char* ws = (char*)d_ws;
  unsigned short* ws_wihs = (unsigned short*)(ws + 0);        // 49152
  unsigned short* ws_wihr = (unsigned short*)(ws + 49152);    // 49152
  unsigned short* ws_whh0 = (unsigned short*)(ws + 98304);    // 393216
  unsigned short* ws_wih1 = (unsigned short*)(ws + 491520);   // 393216
  unsigned short* ws_whh1 = (unsigned short*)(ws + 884736);   // 393216
  float* h0 = (float*)(ws + 1277952);                          // 2 MiB
  float* h1 = (float*)(ws + 3375104);                          // 2 MiB
  const size_t base = 5472256;

  // per chunk: 2x out0 (Tc MiB each) + xg1c (3*Tc MiB) = 5*Tc MiB
  int Tc = 1;
  const int cands[7] = {25, 20, 10, 5, 4, 2, 1};
  for (int i = 0; i < 7; ++i) {
    size_t need = base + (size_t)5242880 * cands[i];
    if (need <= ws_size) { Tc = cands[i]; break; }
  }
  unsigned short* out0A = (unsigned short*)(ws + base);
  unsigned short* out0B = (unsigned short*)(ws + base + (size_t)1048576 * Tc);
  unsigned short* xg1c  = (unsigned short*)(ws + base + (size_t)2097152 * Tc);
  const int nc = 100 / Tc;

  const long total_prep = 2 * 768L * 32 + 3 * 768L * 256 + 2 * 2048L * 256;
  k_prep<<<(int)((total_prep + 255) / 256), 256, 0, stream>>>(
      wih0, whh0, wih1, whh1, ws_wihs, ws_wihr, ws_whh0, ws_wih1, ws_whh1, h0, h1);

  // 2-stage pipeline: launch c = L0(c) writing out0[c&1]  ||  L1(c-1) with a
  // self-serve xg1 pre-phase reading out0[(c-1)&1]. Stream order gives deps.
  for (int c = 0; c <= nc; ++c) {
    unsigned short* o0w = (c & 1) ? out0B : out0A;
    const unsigned short* o0r = (c & 1) ? out0A : out0B;  // (c-1)&1 parity
    k_fused<<<256, THREADS, 0, stream>>>(
        obs, ws_wihs, ws_wihr, ws_whh0, bih0, bhh0, h0, o0w, o0r,
        xg1c, ws_wih1, ws_whh1, bih1, bhh1, h1,
        fcw, fcb, ahigh, alow, (float*)d_out,
        c * Tc, Tc, (c < nc) ? 1 : 0, (c > 0) ? 1 : 0, (c == nc) ? 1 : 0);
  }
}

// Round 9
// 650.157 us; speedup vs baseline: 1.0993x; 1.0993x over previous
//
#include <hip/hip_runtime.h>
#include <hip/hip_bf16.h>
#include <stdint.h>
#include <stddef.h>

// GRU policy: B=2048, T=100, H=256, IN=48 (32 state + 16 ref), ACT=2.
// R9: R8's xg fold-in, fixed. Role1 pre-phase now stages out0(c-1) B-tiles
//     through LDS (s_hA region, double-buffered; one cooperative 8KB load
//     per WG per tt, shared by all 8 waves) with forced prefetch confirmed
//     via vmcnt(24) (R7-validated: 24 xg stores issued after the load).
//     Pre-phase live regs: af 192 + Cx 24 + stg 8 ~= 236 < 256 -> no spill.
//     5 fused launches + prep; no k_xg1 kernel.

#define OBS_STRIDE 1632
#define H 256
#define M 16
#define THREADS 512

typedef __attribute__((ext_vector_type(8))) short bfrag8;   // 8 bf16 (4 VGPR)
typedef __attribute__((ext_vector_type(4))) short bfrag4;   // 4 bf16 (8B)
typedef __attribute__((ext_vector_type(4))) float floatx4;  // MFMA C/D

#define MFMA16(a, b, c) __builtin_amdgcn_mfma_f32_16x16x32_bf16((a), (b), (c), 0, 0, 0)

__device__ __forceinline__ unsigned short f2bf(float f) {
  union { float f; unsigned int i; } v; v.f = f;
  unsigned int i = v.i + 0x7FFFu + ((v.i >> 16) & 1u);  // RNE
  return (unsigned short)(i >> 16);
}
__device__ __forceinline__ float bf2f(unsigned short u) {
  union { unsigned int i; float f; } v; v.i = ((unsigned int)u) << 16; return v.f;
}
// sigmoid(x) = rcp(1 + 2^(-x*log2e)); saturates correctly, no clamps.
__device__ __forceinline__ float fsigm(float x) {
  return __builtin_amdgcn_rcpf(1.f + __builtin_amdgcn_exp2f(-1.44269504f * x));
}
// tanh(x) = 1 - 2*rcp(1 + 2^(x*2log2e)); saturates correctly, no clamps.
__device__ __forceinline__ float ftanh(float x) {
  return 1.f - 2.f * __builtin_amdgcn_rcpf(1.f + __builtin_amdgcn_exp2f(2.88539008f * x));
}

// Forced (non-rematerializable) 16B global load -> stays in VGPR/AGPR file.
__device__ __forceinline__ void ld16_async(bfrag8& d, const unsigned short* p) {
  asm volatile("global_load_dwordx4 %0, %1, off" : "=v"(d) : "v"(p));
}
__device__ __forceinline__ void wait6(bfrag8& a, bfrag8& b, bfrag8& c,
                                      bfrag8& d, bfrag8& e, bfrag8& f) {
  asm volatile("s_waitcnt vmcnt(0)"
               : "+v"(a), "+v"(b), "+v"(c), "+v"(d), "+v"(e), "+v"(f) :: "memory");
}
__device__ __forceinline__ void wait_vm0(bfrag8& a) {
  asm volatile("s_waitcnt vmcnt(0)" : "+v"(a) :: "memory");
}
// In-order vmcnt retirement: load issued BEFORE the 24 stores of the same
// iteration -> vmcnt(24) guarantees the load retired (R7-validated).
__device__ __forceinline__ void wait_vm24(bfrag8& a) {
  asm volatile("s_waitcnt vmcnt(24)" : "+v"(a) :: "memory");
}
// Workgroup barrier draining LDS only (skips vmcnt(0) store-ack drain).
__device__ __forceinline__ void barrier_lgkm() {
  asm volatile("s_waitcnt lgkmcnt(0)\n\ts_barrier" ::: "memory");
}

// ---------------------------------------------------------------- k_prep
__global__ void k_prep(const float* __restrict__ wih0, const float* __restrict__ whh0,
                       const float* __restrict__ wih1, const float* __restrict__ whh1,
                       unsigned short* __restrict__ o_wihs, unsigned short* __restrict__ o_wihr,
                       unsigned short* __restrict__ o_whh0,
                       unsigned short* __restrict__ o_wih1, unsigned short* __restrict__ o_whh1,
                       float* __restrict__ h0, float* __restrict__ h1) {
  long idx = (long)blockIdx.x * blockDim.x + threadIdx.x;
  const long ns = 768L * 32, n1 = 768L * 256, nh = 2048L * 256;
  if (idx < ns) { long r = idx >> 5, c = idx & 31;
                  o_wihs[idx] = f2bf(wih0[r * 48 + c]); return; }
  idx -= ns;
  if (idx < ns) { long r = idx >> 5, c = idx & 31;
                  o_wihr[idx] = (c < 16) ? f2bf(wih0[r * 48 + 32 + c]) : (unsigned short)0; return; }
  idx -= ns;
  if (idx < n1) { o_whh0[idx] = f2bf(whh0[idx]); return; }
  idx -= n1;
  if (idx < n1) { o_wih1[idx] = f2bf(wih1[idx]); return; }
  idx -= n1;
  if (idx < n1) { o_whh1[idx] = f2bf(whh1[idx]); return; }
  idx -= n1;
  if (idx < nh) { h0[idx] = 0.f; return; }
  idx -= nh;
  if (idx < nh) { h1[idx] = 0.f; return; }
}

// ---------------------------------------------------------------- k_fused
// 256 WGs: blocks 0..127 = layer0 chunk c, blocks 128..255 = layer1 chunk c-1
// (LDS-pipelined self-serve xg1 pre-phase reading out0(c-1)).
// Per role: 16 batch rows/WG. Wave wv owns h-cols [32wv,32wv+32):
// tiles f0..5={r0,r1,z0,z1,n0,n1}, nt=(f>>1)*16+2*wv+(f&1).
__global__ __launch_bounds__(THREADS, 2) void k_fused(
    const float* __restrict__ obs,
    const unsigned short* __restrict__ g_wihs,  // [768][32]
    const unsigned short* __restrict__ g_wihr,  // [768][32] (hi 16 zero)
    const unsigned short* __restrict__ g_whh0,  // [768][256]
    const float* __restrict__ b_ih0, const float* __restrict__ b_hh0,
    float* __restrict__ h0state,
    unsigned short* __restrict__ out0w,         // [Tc][2048][256]  (role0 writes)
    const unsigned short* __restrict__ out0r,   // [Tc][2048][256]  (role1 reads)
    unsigned short* __restrict__ xg1c,          // [Tc][128][768][16] (role1 w+r)
    const unsigned short* __restrict__ g_wih1,  // [768][256]
    const unsigned short* __restrict__ g_whh1,  // [768][256]
    const float* __restrict__ b_ih1, const float* __restrict__ b_hh1,
    float* __restrict__ h1state,
    const float* __restrict__ fc_w, const float* __restrict__ fc_b,
    const float* __restrict__ act_high, const float* __restrict__ act_low,
    float* __restrict__ dout,
    int t0, int Tc, int do_l0, int do_l1, int is_last) {
  __shared__ __align__(16) unsigned short s_mem[71936];

  const int tid = threadIdx.x;
  const int wv = tid >> 6, lane = tid & 63, ln = lane & 15, qd = lane >> 4;
  const int role = blockIdx.x >> 7;          // 0 = layer0, 1 = layer1
  const int bblk = blockIdx.x & 127;
  const int b0 = bblk * M;

  if (role == 0) {
    // ======================= LAYER 0 =======================
    if (!do_l0) return;
    unsigned short* s_whh6 = s_mem;           // [768*40]
    unsigned short* s_whh7 = s_mem + 30720;   // [768*40]
    unsigned short* s_hA   = s_mem + 61440;   // [2][16*264]
    unsigned short* s_x    = s_mem + 69888;   // [2][16*32]
    unsigned short* s_st   = s_mem + 70912;   // [16*32]

    for (int i = tid * 8; i < 768 * 32; i += THREADS * 8) {
      int m = i >> 5, c = i & 31;
      *(bfrag8*)&s_whh6[m * 40 + c] = *(const bfrag8*)&g_whh0[m * 256 + 192 + c];
      *(bfrag8*)&s_whh7[m * 40 + c] = *(const bfrag8*)&g_whh0[m * 256 + 224 + c];
    }
    { int r = tid >> 5, c = tid & 31;
      s_st[tid] = f2bf(obs[(size_t)(b0 + r) * OBS_STRIDE + c]); }
    if (tid < 256) {
      int r = tid >> 4, c = tid & 15;
      s_x[r * 32 + c] = f2bf(obs[(size_t)(b0 + r) * OBS_STRIDE + 32 + (size_t)t0 * 16 + c]);
      s_x[r * 32 + 16 + c] = 0;
      s_x[512 + r * 32 + 16 + c] = 0;
    }

    bfrag8 wf[6][6];  // forced-resident w_hh0 ks0..5
#pragma unroll
    for (int ks = 0; ks < 6; ++ks) {
#pragma unroll
      for (int f = 0; f < 6; ++f) {
        int nt = (f >> 1) * 16 + 2 * wv + (f & 1);
        ld16_async(wf[f][ks], g_whh0 + (size_t)(nt * 16 + ln) * 256 + ks * 32 + qd * 8);
      }
      wait6(wf[0][ks], wf[1][ks], wf[2][ks], wf[3][ks], wf[4][ks], wf[5][ks]);
    }
    bfrag8 wir[6];
#pragma unroll
    for (int f = 0; f < 6; ++f) {
      int nt = (f >> 1) * 16 + 2 * wv + (f & 1);
      wir[f] = *(const bfrag8*)&g_wihr[(size_t)(nt * 16 + ln) * 32 + qd * 8];
    }
    float bias_hn[2];
#pragma unroll
    for (int p = 0; p < 2; ++p) bias_hn[p] = b_hh0[512 + wv * 32 + p * 16 + ln];

    float h[2][4];
#pragma unroll
    for (int p = 0; p < 2; ++p)
#pragma unroll
      for (int i = 0; i < 4; ++i)
        h[p][i] = h0state[(size_t)(b0 + qd * 4 + i) * H + wv * 32 + p * 16 + ln];

    __syncthreads();

    // time-invariant state GEMM + bias fold
    floatx4 cc[6];
    {
      bfrag8 a_st = *(const bfrag8*)&s_st[ln * 32 + qd * 8];
#pragma unroll
      for (int f = 0; f < 6; ++f) {
        int nt = (f >> 1) * 16 + 2 * wv + (f & 1);
        int m = nt * 16 + ln;
        bfrag8 b_st = *(const bfrag8*)&g_wihs[(size_t)m * 32 + qd * 8];
        cc[f] = MFMA16(a_st, b_st, ((floatx4){0.f, 0.f, 0.f, 0.f}));
        float badd = b_ih0[m] + ((f < 4) ? b_hh0[m] : 0.f);
#pragma unroll
        for (int i = 0; i < 4; ++i) cc[f][i] += badd;
      }
    }
#pragma unroll
    for (int p = 0; p < 2; ++p)
#pragma unroll
      for (int i = 0; i < 4; ++i)
        s_hA[(qd * 4 + i) * 264 + wv * 32 + p * 16 + ln] = f2bf(h[p][i]);
    __syncthreads();

    const int orow = tid >> 5, ocol = (tid & 31) * 8;
    for (int tt = 0; tt < Tc; ++tt) {
      const int cur = tt & 1, nxt = cur ^ 1;
      // coalesced out0 store of PREVIOUS step's h from s_hA[cur] (stable now)
      if (tt > 0) {
        bfrag8 hv = *(const bfrag8*)&s_hA[cur * 4224 + orow * 264 + ocol];
        *(bfrag8*)&out0w[((size_t)(tt - 1) * 2048 + b0 + orow) * 256 + ocol] = hv;
      }
      float nref = 0.f;
      {
        int tl = (tt + 1 < Tc) ? tt + 1 : tt;
        if (tid < 256)
          nref = obs[(size_t)(b0 + (tid >> 4)) * OBS_STRIDE + 32 +
                     (size_t)(t0 + tl) * 16 + (tid & 15)];
      }

      floatx4 C[8];  // 0,1=r 2,3=z 4,5=xn 6,7=hn
#pragma unroll
      for (int f = 0; f < 6; ++f) C[f] = cc[f];
      C[6] = (floatx4){0.f, 0.f, 0.f, 0.f};
      C[7] = (floatx4){0.f, 0.f, 0.f, 0.f};

      {  // ref GEMM (K=32, hi half zero)
        bfrag8 ax = *(const bfrag8*)&s_x[cur * 512 + ln * 32 + qd * 8];
        C[0] = MFMA16(ax, wir[0], C[0]);
        C[1] = MFMA16(ax, wir[1], C[1]);
        C[2] = MFMA16(ax, wir[2], C[2]);
        C[3] = MFMA16(ax, wir[3], C[3]);
        C[4] = MFMA16(ax, wir[4], C[4]);
        C[5] = MFMA16(ax, wir[5], C[5]);
      }
#pragma unroll
      for (int ks = 0; ks < 6; ++ks) {
        bfrag8 ah = *(const bfrag8*)&s_hA[cur * 4224 + ln * 264 + ks * 32 + qd * 8];
        C[0] = MFMA16(ah, wf[0][ks], C[0]);
        C[1] = MFMA16(ah, wf[1][ks], C[1]);
        C[2] = MFMA16(ah, wf[2][ks], C[2]);
        C[3] = MFMA16(ah, wf[3][ks], C[3]);
        C[6] = MFMA16(ah, wf[4][ks], C[6]);
        C[7] = MFMA16(ah, wf[5][ks], C[7]);
      }
      {  // ks6 strip
        bfrag8 ah = *(const bfrag8*)&s_hA[cur * 4224 + ln * 264 + 192 + qd * 8];
#pragma unroll
        for (int f = 0; f < 6; ++f) {
          int nt = (f >> 1) * 16 + 2 * wv + (f & 1);
          bfrag8 bh = *(const bfrag8*)&s_whh6[(nt * 16 + ln) * 40 + qd * 8];
          int ci = (f < 4) ? f : f + 2;
          C[ci] = MFMA16(ah, bh, C[ci]);
        }
      }
      {  // ks7 strip
        bfrag8 ah = *(const bfrag8*)&s_hA[cur * 4224 + ln * 264 + 224 + qd * 8];
#pragma unroll
        for (int f = 0; f < 6; ++f) {
          int nt = (f >> 1) * 16 + 2 * wv + (f & 1);
          bfrag8 bh = *(const bfrag8*)&s_whh7[(nt * 16 + ln) * 40 + qd * 8];
          int ci = (f < 4) ? f : f + 2;
          C[ci] = MFMA16(ah, bh, C[ci]);
        }
      }
#pragma unroll
      for (int p = 0; p < 2; ++p)
#pragma unroll
        for (int i = 0; i < 4; ++i) {
          float r = fsigm(C[0 + p][i]);
          float z = fsigm(C[2 + p][i]);
          float n = ftanh(C[4 + p][i] + r * (C[6 + p][i] + bias_hn[p]));
          h[p][i] = n + z * (h[p][i] - n);
          s_hA[nxt * 4224 + (qd * 4 + i) * 264 + wv * 32 + p * 16 + ln] = f2bf(h[p][i]);
        }
      if (tid < 256) s_x[nxt * 512 + (tid >> 4) * 32 + (tid & 15)] = f2bf(nref);
      barrier_lgkm();
    }
    // final out0 store + h0 carry
    {
      const int fb = Tc & 1;
      bfrag8 hv = *(const bfrag8*)&s_hA[fb * 4224 + orow * 264 + ocol];
      *(bfrag8*)&out0w[((size_t)(Tc - 1) * 2048 + b0 + orow) * 256 + ocol] = hv;
    }
#pragma unroll
    for (int p = 0; p < 2; ++p)
#pragma unroll
      for (int i = 0; i < 4; ++i)
        h0state[(size_t)(b0 + qd * 4 + i) * H + wv * 32 + p * 16 + ln] = h[p][i];

  } else {
    // ======================= LAYER 1 =======================
    if (!do_l1) return;
    unsigned short* s_whh7 = s_mem;           // [768*40]
    unsigned short* s_hA   = s_mem + 30720;   // [2][16*264] (pre-phase: B dbuf)

    const int orow = tid >> 5, ocol = (tid & 31) * 8;

    // ---- PRE-PHASE: compute this WG's xg1 slice from out0r ----
    // B-tile (16x256) staged cooperatively through LDS (shared by all 8
    // waves), double-buffered in the s_hA region; forced prefetch confirmed
    // by vmcnt(24). af released before wf loads (disjoint lifetimes).
    {
      bfrag8 af[6][8];  // forced-resident w_ih_l1 A-fragments (192 regs)
#pragma unroll
      for (int ks = 0; ks < 8; ++ks) {
#pragma unroll
        for (int f = 0; f < 6; ++f) {
          ld16_async(af[f][ks],
                     g_wih1 + (size_t)((wv * 6 + f) * 16 + ln) * 256 + ks * 32 + qd * 8);
        }
        wait6(af[0][ks], af[1][ks], af[2][ks], af[3][ks], af[4][ks], af[5][ks]);
      }
      // prologue: stage tile tt=0
      bfrag8 stg;
      ld16_async(stg, out0r + ((size_t)(b0 + orow)) * 256 + ocol);
      wait_vm0(stg);
      *(bfrag8*)&s_hA[orow * 264 + ocol] = stg;
      barrier_lgkm();

      for (int tt = 0; tt < Tc; ++tt) {
        const int cur = tt & 1, nxt = cur ^ 1;
        // 1) prefetch tile tt+1 (oldest vm op of this iteration)
        if (tt + 1 < Tc)
          ld16_async(stg, out0r + ((size_t)(tt + 1) * 2048 + b0 + orow) * 256 + ocol);
        // 2) MFMA on tile tt from LDS
        floatx4 Cx[6];
#pragma unroll
        for (int f = 0; f < 6; ++f) Cx[f] = (floatx4){0.f, 0.f, 0.f, 0.f};
#pragma unroll
        for (int ks = 0; ks < 8; ++ks) {
          bfrag8 bfr = *(const bfrag8*)&s_hA[cur * 4224 + ln * 264 + ks * 32 + qd * 8];
          Cx[0] = MFMA16(af[0][ks], bfr, Cx[0]);
          Cx[1] = MFMA16(af[1][ks], bfr, Cx[1]);
          Cx[2] = MFMA16(af[2][ks], bfr, Cx[2]);
          Cx[3] = MFMA16(af[3][ks], bfr, Cx[3]);
          Cx[4] = MFMA16(af[4][ks], bfr, Cx[4]);
          Cx[5] = MFMA16(af[5][ks], bfr, Cx[5]);
        }
        // 3) store xg slice (24 2B stores, issued after the prefetch load)
        const size_t obase = ((size_t)tt * 128 + bblk) * (768 * 16);
#pragma unroll
        for (int f = 0; f < 6; ++f) {
          int nt = wv * 6 + f;
#pragma unroll
          for (int i = 0; i < 4; ++i) {
            int m = nt * 16 + qd * 4 + i;
            xg1c[obase + (size_t)m * 16 + ln] = f2bf(Cx[f][i]);
          }
        }
        // 4) land prefetch into the other LDS buffer
        if (tt + 1 < Tc) {
          if (tt == 0) wait_vm0(stg); else wait_vm24(stg);
          *(bfrag8*)&s_hA[nxt * 4224 + orow * 264 + ocol] = stg;
        }
        barrier_lgkm();
      }
    }

    // ---- main phase setup (wf loads' vmcnt(0) waits also drain the
    //      pre-phase xg1c stores before any xg read below) ----
    for (int i = tid * 8; i < 768 * 32; i += THREADS * 8) {
      int m = i >> 5, c = i & 31;
      *(bfrag8*)&s_whh7[m * 40 + c] = *(const bfrag8*)&g_whh1[m * 256 + 224 + c];
    }
    bfrag8 wf[6][7];  // forced-resident w_hh1 ks0..6
#pragma unroll
    for (int ks = 0; ks < 7; ++ks) {
#pragma unroll
      for (int f = 0; f < 6; ++f) {
        int nt = (f >> 1) * 16 + 2 * wv + (f & 1);
        ld16_async(wf[f][ks], g_whh1 + (size_t)(nt * 16 + ln) * 256 + ks * 32 + qd * 8);
      }
      wait6(wf[0][ks], wf[1][ks], wf[2][ks], wf[3][ks], wf[4][ks], wf[5][ks]);
    }
    float bias_r[2], bias_z[2], bias_xn[2], bias_hn[2];
#pragma unroll
    for (int p = 0; p < 2; ++p) {
      int col = wv * 32 + p * 16 + ln;
      bias_r[p] = b_ih1[col] + b_hh1[col];
      bias_z[p] = b_ih1[256 + col] + b_hh1[256 + col];
      bias_xn[p] = b_ih1[512 + col];
      bias_hn[p] = b_hh1[512 + col];
    }
    float h[2][4];
#pragma unroll
    for (int p = 0; p < 2; ++p)
#pragma unroll
      for (int i = 0; i < 4; ++i)
        h[p][i] = h1state[(size_t)(b0 + qd * 4 + i) * H + wv * 32 + p * 16 + ln];
    barrier_lgkm();  // pre-phase LDS fully consumed before h overwrite
#pragma unroll
    for (int p = 0; p < 2; ++p)
#pragma unroll
      for (int i = 0; i < 4; ++i)
        s_hA[(qd * 4 + i) * 264 + wv * 32 + p * 16 + ln] = f2bf(h[p][i]);

    size_t offx[2][3];
#pragma unroll
    for (int p = 0; p < 2; ++p) {
      int col = wv * 32 + p * 16 + ln;
#pragma unroll
      for (int g = 0; g < 3; ++g)
        offx[p][g] = (size_t)(g * 256 + col) * 16 + qd * 4;
    }
    bfrag4 xr[2], xz[2], xn[2];
    {
      const unsigned short* xb = xg1c + (size_t)bblk * (768 * 16);
#pragma unroll
      for (int p = 0; p < 2; ++p) {
        xr[p] = *(const bfrag4*)&xb[offx[p][0]];
        xz[p] = *(const bfrag4*)&xb[offx[p][1]];
        xn[p] = *(const bfrag4*)&xb[offx[p][2]];
      }
    }
    __syncthreads();

    for (int tt = 0; tt < Tc; ++tt) {
      const int cur = tt & 1, nxt = cur ^ 1;
      bfrag4 nxr[2], nxz[2], nxn[2];
      {
        int tl = (tt + 1 < Tc) ? tt + 1 : tt;
        const unsigned short* xb = xg1c + ((size_t)tl * 128 + bblk) * (768 * 16);
#pragma unroll
        for (int p = 0; p < 2; ++p) {
          nxr[p] = *(const bfrag4*)&xb[offx[p][0]];
          nxz[p] = *(const bfrag4*)&xb[offx[p][1]];
          nxn[p] = *(const bfrag4*)&xb[offx[p][2]];
        }
      }

      floatx4 C[6];  // 0,1=r 2,3=z 4,5=hn
#pragma unroll
      for (int i = 0; i < 6; ++i) C[i] = (floatx4){0.f, 0.f, 0.f, 0.f};
#pragma unroll
      for (int ks = 0; ks < 7; ++ks) {
        bfrag8 ah = *(const bfrag8*)&s_hA[cur * 4224 + ln * 264 + ks * 32 + qd * 8];
        C[0] = MFMA16(ah, wf[0][ks], C[0]);
        C[1] = MFMA16(ah, wf[1][ks], C[1]);
        C[2] = MFMA16(ah, wf[2][ks], C[2]);
        C[3] = MFMA16(ah, wf[3][ks], C[3]);
        C[4] = MFMA16(ah, wf[4][ks], C[4]);
        C[5] = MFMA16(ah, wf[5][ks], C[5]);
      }
      {
        bfrag8 ah = *(const bfrag8*)&s_hA[cur * 4224 + ln * 264 + 224 + qd * 8];
#pragma unroll
        for (int f = 0; f < 6; ++f) {
          int nt = (f >> 1) * 16 + 2 * wv + (f & 1);
          bfrag8 bh = *(const bfrag8*)&s_whh7[(nt * 16 + ln) * 40 + qd * 8];
          C[f] = MFMA16(ah, bh, C[f]);
        }
      }
#pragma unroll
      for (int p = 0; p < 2; ++p)
#pragma unroll
        for (int i = 0; i < 4; ++i) {
          float r = fsigm(C[0 + p][i] + bf2f((unsigned short)xr[p][i]) + bias_r[p]);
          float z = fsigm(C[2 + p][i] + bf2f((unsigned short)xz[p][i]) + bias_z[p]);
          float n = ftanh(bf2f((unsigned short)xn[p][i]) + bias_xn[p] +
                          r * (C[4 + p][i] + bias_hn[p]));
          h[p][i] = n + z * (h[p][i] - n);
          s_hA[nxt * 4224 + (qd * 4 + i) * 264 + wv * 32 + p * 16 + ln] = f2bf(h[p][i]);
        }
#pragma unroll
      for (int p = 0; p < 2; ++p) { xr[p] = nxr[p]; xz[p] = nxz[p]; xn[p] = nxn[p]; }
      barrier_lgkm();
    }
#pragma unroll
    for (int p = 0; p < 2; ++p)
#pragma unroll
      for (int i = 0; i < 4; ++i)
        h1state[(size_t)(b0 + qd * 4 + i) * H + wv * 32 + p * 16 + ln] = h[p][i];

    if (is_last) {
      // parallel FC tail: tid = r*32 + a*16 + kseg
      const int fb = Tc & 1;
      int r = tid >> 5, a = (tid >> 4) & 1, kseg = tid & 15;
      float acc = 0.f;
#pragma unroll
      for (int j = 0; j < 16; ++j) {
        int k = kseg * 16 + j;
        acc += bf2f(s_hA[fb * 4224 + r * 264 + k]) * fc_w[a * H + k];
      }
      acc += __shfl_down(acc, 8);
      acc += __shfl_down(acc, 4);
      acc += __shfl_down(acc, 2);
      acc += __shfl_down(acc, 1);
      if (kseg == 0) {
        acc += fc_b[a];
        float hi = act_high[a], lo = act_low[a];
        float th = ftanh(acc);
        dout[(size_t)(b0 + r) * 2 + a] = 0.5f * (hi - lo) * th + 0.5f * (hi + lo);
      }
    }
  }
}

// ---------------------------------------------------------------- host
extern "C" void kernel_launch(void* const* d_in, const int* in_sizes, int n_in,
                              void* d_out, int out_size, void* d_ws, size_t ws_size,
                              hipStream_t stream) {
  const float* obs  = (const float*)d_in[0];
  const float* wih0 = (const float*)d_in[1];
  const float* whh0 = (const float*)d_in[2];
  const float* bih0 = (const float*)d_in[3];
  const float* bhh0 = (const float*)d_in[4];
  const float* wih1 = (const float*)d_in[5];
  const float* whh1 = (const float*)d_in[6];
  const float* bih1 = (const float*)d_in[7];
  const float* bhh1 = (const float*)d_in[8];
  const float* fcw  = (const float*)d_in[9];
  const float* fcb  = (const float*)d_in[10];
  const float* ahigh= (const float*)d_in[11];
  const float* alow = (const float*)d_in[12];

  char* ws = (char*)d_ws;
  unsigned short* ws_wihs = (unsigned short*)(ws + 0);        // 49152
  unsigned short* ws_wihr = (unsigned short*)(ws + 49152);    // 49152
  unsigned short* ws_whh0 = (unsigned short*)(ws + 98304);    // 393216
  unsigned short* ws_wih1 = (unsigned short*)(ws + 491520);   // 393216
  unsigned short* ws_whh1 = (unsigned short*)(ws + 884736);   // 393216
  float* h0 = (float*)(ws + 1277952);                          // 2 MiB
  float* h1 = (float*)(ws + 3375104);                          // 2 MiB
  const size_t base = 5472256;

  // per chunk: 2x out0 (Tc MiB each) + xg1c (3*Tc MiB) = 5*Tc MiB
  int Tc = 1;
  const int cands[7] = {25, 20, 10, 5, 4, 2, 1};
  for (int i = 0; i < 7; ++i) {
    size_t need = base + (size_t)5242880 * cands[i];
    if (need <= ws_size) { Tc = cands[i]; break; }
  }
  unsigned short* out0A = (unsigned short*)(ws + base);
  unsigned short* out0B = (unsigned short*)(ws + base + (size_t)1048576 * Tc);
  unsigned short* xg1c  = (unsigned short*)(ws + base + (size_t)2097152 * Tc);
  const int nc = 100 / Tc;

  const long total_prep = 2 * 768L * 32 + 3 * 768L * 256 + 2 * 2048L * 256;
  k_prep<<<(int)((total_prep + 255) / 256), 256, 0, stream>>>(
      wih0, whh0, wih1, whh1, ws_wihs, ws_wihr, ws_whh0, ws_wih1, ws_whh1, h0, h1);

  // 2-stage pipeline: launch c = L0(c) writing out0[c&1]  ||  L1(c-1) with an
  // LDS-pipelined xg1 pre-phase reading out0[(c-1)&1]. Stream order = deps.
  for (int c = 0; c <= nc; ++c) {
    unsigned short* o0w = (c & 1) ? out0B : out0A;
    const unsigned short* o0r = (c & 1) ? out0A : out0B;  // (c-1)&1 parity
    k_fused<<<256, THREADS, 0, stream>>>(
        obs, ws_wihs, ws_wihr, ws_whh0, bih0, bhh0, h0, o0w, o0r,
        xg1c, ws_wih1, ws_whh1, bih1, bhh1, h1,
        fcw, fcb, ahigh, alow, (float*)d_out,
        c * Tc, Tc, (c < nc) ? 1 : 0, (c > 0) ? 1 : 0, (c == nc) ? 1 : 0);
  }
}